// Round 1
// baseline (429.395 us; speedup 1.0000x reference)
//
#include <hip/hip_runtime.h>

// y[0,:] = x[0,:]
// y[i,:] = x[i,:] + x[i-1,:]*w[i-1] + b[i-1]   (i = 1..H-1)
//
// Register-tiled: each block owns an 8-row x 256-float4 column tile.
// It loads 9 row segments (r0-1 .. r0+7) and produces 8 output rows,
// so every x element is loaded ONCE per block (9/8 read amplification,
// and the shared boundary row is an L2 hit from a same-XCD neighbor
// block) instead of the previous version's 2 loads per output element.
// 9 independent 16B loads per thread -> deep memory-level parallelism.
// w/b indices are block-uniform -> scalar (s_load) paths.
// Nontemporal stores keep the write stream from evicting x in L2/L3.

#define H_DIM 8192
#define D_DIM 8192
#define D4 (D_DIM / 4)          // 2048 float4 per row
#define ROWS 8                  // rows per block tile
#define BLOCK 256               // float4 columns per block tile

typedef float v4f __attribute__((ext_vector_type(4)));

__global__ __launch_bounds__(BLOCK, 4) void lateral_kernel(
    const v4f* __restrict__ x,
    const float* __restrict__ w,
    const float* __restrict__ b,
    v4f* __restrict__ y) {

    const int r0   = blockIdx.y * ROWS;                 // first output row of tile
    const int c    = blockIdx.x * BLOCK + threadIdx.x;  // float4 column
    const int base = r0 * D4 + c;

    // Issue all tile loads up front (independent -> MLP).
    v4f xs[ROWS];
    #pragma unroll
    for (int j = 0; j < ROWS; ++j)
        xs[j] = x[base + j * D4];

    v4f prev = {0.f, 0.f, 0.f, 0.f};
    if (r0 > 0)
        prev = x[base - D4];                            // boundary row (L2 hit)

    // Block-uniform weight/bias loads (scalarizable).
    float wr[ROWS], br[ROWS];
    #pragma unroll
    for (int j = 0; j < ROWS; ++j) {
        const int row = r0 + j;
        wr[j] = (row > 0) ? w[row - 1] : 0.f;
        br[j] = (row > 0) ? b[row - 1] : 0.f;
    }

    // Compute 8 output rows from registers; each xs[j] reused as the
    // "previous row" of the next output -> zero extra memory traffic.
    v4f o[ROWS];
    v4f p = prev;
    #pragma unroll
    for (int j = 0; j < ROWS; ++j) {
        const v4f cur = xs[j];
        v4f oo;
        oo.x = fmaf(p.x, wr[j], cur.x + br[j]);
        oo.y = fmaf(p.y, wr[j], cur.y + br[j]);
        oo.z = fmaf(p.z, wr[j], cur.z + br[j]);
        oo.w = fmaf(p.w, wr[j], cur.w + br[j]);
        o[j] = oo;
        p = cur;
    }
    if (r0 == 0)
        o[0] = xs[0];                                   // row 0 pass-through

    #pragma unroll
    for (int j = 0; j < ROWS; ++j)
        __builtin_nontemporal_store(o[j], &y[base + j * D4]);
}

extern "C" void kernel_launch(void* const* d_in, const int* in_sizes, int n_in,
                              void* d_out, int out_size, void* d_ws, size_t ws_size,
                              hipStream_t stream) {
    const v4f*   x = (const v4f*)d_in[0];
    const float* w = (const float*)d_in[1];
    const float* b = (const float*)d_in[2];
    v4f* y = (v4f*)d_out;

    dim3 grid(D4 / BLOCK, H_DIM / ROWS);   // (8, 1024): column strips fastest
    lateral_kernel<<<grid, BLOCK, 0, stream>>>(x, w, b, y);
}